// Round 1
// baseline (1590.086 us; speedup 1.0000x reference)
//
#include <hip/hip_runtime.h>

#define DEPTH 18
#define EMB 128
#define HID 256
#define VAL 32
#define N_LEAVES (1 << DEPTH)
#define LEAF_START (N_LEAVES - 1)

__device__ __forceinline__ float lrelu(float x) { return x > 0.f ? x : 0.01f * x; }

// ---------------------------------------------------------------------------
// Kernel 1: leaf embedding  lrelu(leaf_values @ We + be) -> embs[LEAF_START..]
// Block: 256 threads = (j in 0..127, half in 0..1); 16 leaves per block.
// We column per-thread in registers; leaf rows staged in LDS (broadcast reads).
// ---------------------------------------------------------------------------
__global__ __launch_bounds__(256) void leaf_embed(
    const float* __restrict__ lv, const float* __restrict__ We,
    const float* __restrict__ be, float* __restrict__ embs)
{
    __shared__ float lvs[16][VAL];   // 2 KB
    const int j = threadIdx.x & 127;
    const int h = threadIdx.x >> 7;  // 0 or 1

    float w[VAL];
#pragma unroll
    for (int k = 0; k < VAL; ++k) w[k] = We[k * EMB + j];
    const float bj = be[j];

    const int leaf0 = blockIdx.x * 16;
    {   // stage 16 leaf rows = 512 floats, coalesced
        const float* src = lv + (size_t)leaf0 * VAL;
        ((float*)lvs)[threadIdx.x]       = src[threadIdx.x];
        ((float*)lvs)[threadIdx.x + 256] = src[threadIdx.x + 256];
    }
    __syncthreads();

#pragma unroll
    for (int it = 0; it < 8; ++it) {
        const int ll = it * 2 + h;          // wave-uniform -> LDS broadcast
        float acc = bj;
#pragma unroll
        for (int k4 = 0; k4 < VAL / 4; ++k4) {
            float4 x4 = *(const float4*)&lvs[ll][k4 * 4];
            acc += x4.x * w[k4*4] + x4.y * w[k4*4+1] + x4.z * w[k4*4+2] + x4.w * w[k4*4+3];
        }
        embs[(size_t)(LEAF_START + leaf0 + ll) * EMB + j] = lrelu(acc);
    }
}

// ---------------------------------------------------------------------------
// Kernel 2: one tree level (n >= 32, n % 32 == 0).
// out[p0+i] = lrelu(lrelu(X[i] @ W1 + b1) @ W2 + b2),
// X = embs viewed flat from (2*p0+1)*EMB, 32 rows per block.
// LDS: X/H tile (32x256, reused) + weight chunk staging (BK=32). 64 KB total.
// GEMM1 register tile 4x8 (256 threads = 8 row-groups x 32 col-groups);
// GEMM2 register tile 4x4.
// ---------------------------------------------------------------------------
__global__ __launch_bounds__(256) void level_mlp(
    const float* __restrict__ W1, const float* __restrict__ b1,
    const float* __restrict__ W2, const float* __restrict__ b2,
    float* __restrict__ embs, int p0)
{
    __shared__ float XH[32 * HID];   // 32 KB: X tile, later overwritten with H
    __shared__ float Ws[32 * HID];   // 32 KB: weight chunk staging

    const int tid = threadIdx.x;
    const int tx = tid & 31;         // col group
    const int ty = tid >> 5;         // row group 0..7 (4 rows each)

    // ---- stage X tile: 32 rows x 256 = 8192 floats ----
    const float4* Xv = (const float4*)(embs + ((size_t)(2 * p0 + 1) + (size_t)blockIdx.x * 64) * EMB);
    {
        float4* XHv = (float4*)XH;
#pragma unroll
        for (int t = 0; t < 8; ++t) XHv[t * 256 + tid] = Xv[t * 256 + tid];
    }

    // ---- GEMM1: cols j = tx*8..+7, rows r = ty*4..+3 ----
    float acc[4][8];
    {
        float4 blo = *(const float4*)(b1 + tx * 8);
        float4 bhi = *(const float4*)(b1 + tx * 8 + 4);
#pragma unroll
        for (int i = 0; i < 4; ++i) {
            acc[i][0] = blo.x; acc[i][1] = blo.y; acc[i][2] = blo.z; acc[i][3] = blo.w;
            acc[i][4] = bhi.x; acc[i][5] = bhi.y; acc[i][6] = bhi.z; acc[i][7] = bhi.w;
        }
    }
    const float4* W1v = (const float4*)W1;
#pragma unroll 1
    for (int kb = 0; kb < 8; ++kb) {
        __syncthreads();   // also covers initial X staging / previous Ws reads
        {   // stage W1 rows kb*32..+31: 8192 floats
            float4* Wsv = (float4*)Ws;
#pragma unroll
            for (int t = 0; t < 8; ++t) Wsv[t * 256 + tid] = W1v[kb * 2048 + t * 256 + tid];
        }
        __syncthreads();
#pragma unroll
        for (int k4 = 0; k4 < 8; ++k4) {
            float4 x4[4];
#pragma unroll
            for (int i = 0; i < 4; ++i)
                x4[i] = *(const float4*)&XH[(ty * 4 + i) * HID + kb * 32 + k4 * 4];
#pragma unroll
            for (int kk = 0; kk < 4; ++kk) {
                float4 wlo = *(const float4*)&Ws[(k4 * 4 + kk) * HID + tx * 8];
                float4 whi = *(const float4*)&Ws[(k4 * 4 + kk) * HID + tx * 8 + 4];
#pragma unroll
                for (int i = 0; i < 4; ++i) {
                    float xv = ((const float*)&x4[i])[kk];
                    acc[i][0] += xv * wlo.x; acc[i][1] += xv * wlo.y;
                    acc[i][2] += xv * wlo.z; acc[i][3] += xv * wlo.w;
                    acc[i][4] += xv * whi.x; acc[i][5] += xv * whi.y;
                    acc[i][6] += xv * whi.z; acc[i][7] += xv * whi.w;
                }
            }
        }
    }
    __syncthreads();         // all X reads done -> safe to overwrite with H
#pragma unroll
    for (int i = 0; i < 4; ++i)
#pragma unroll
        for (int c = 0; c < 8; ++c)
            XH[(ty * 4 + i) * HID + tx * 8 + c] = lrelu(acc[i][c]);

    // ---- GEMM2: cols j2 = tx*4..+3 (128 cols), rows r = ty*4..+3 ----
    float acc2[4][4];
    {
        float4 b = *(const float4*)(b2 + tx * 4);
#pragma unroll
        for (int i = 0; i < 4; ++i) {
            acc2[i][0] = b.x; acc2[i][1] = b.y; acc2[i][2] = b.z; acc2[i][3] = b.w;
        }
    }
    const float4* W2v = (const float4*)W2;
#pragma unroll 1
    for (int kb = 0; kb < 8; ++kb) {
        __syncthreads();     // covers H writes (first iter) / previous Ws reads
        {   // stage W2 rows kb*32..+31: 4096 floats
            float4* Wsv = (float4*)Ws;
#pragma unroll
            for (int t = 0; t < 4; ++t) Wsv[t * 256 + tid] = W2v[kb * 1024 + t * 256 + tid];
        }
        __syncthreads();
#pragma unroll
        for (int k4 = 0; k4 < 8; ++k4) {
            float4 h4[4];
#pragma unroll
            for (int i = 0; i < 4; ++i)
                h4[i] = *(const float4*)&XH[(ty * 4 + i) * HID + kb * 32 + k4 * 4];
#pragma unroll
            for (int kk = 0; kk < 4; ++kk) {
                float4 w = *(const float4*)&Ws[(k4 * 4 + kk) * EMB + tx * 4];
#pragma unroll
                for (int i = 0; i < 4; ++i) {
                    float hv = ((const float*)&h4[i])[kk];
                    acc2[i][0] += hv * w.x; acc2[i][1] += hv * w.y;
                    acc2[i][2] += hv * w.z; acc2[i][3] += hv * w.w;
                }
            }
        }
    }
    // ---- store 32 output rows ----
    float* Orow = embs + ((size_t)p0 + (size_t)blockIdx.x * 32) * EMB;
#pragma unroll
    for (int i = 0; i < 4; ++i) {
        float4 o;
        o.x = lrelu(acc2[i][0]); o.y = lrelu(acc2[i][1]);
        o.z = lrelu(acc2[i][2]); o.w = lrelu(acc2[i][3]);
        *(float4*)&Orow[(ty * 4 + i) * EMB + tx * 4] = o;
    }
}

// ---------------------------------------------------------------------------
// Kernel 3: levels 4..0 (n = 16..1, 31 nodes total) in ONE block of 1024
// threads, __syncthreads() between levels. Weights read from L2; rows
// register-tiled so each weight load feeds multiple rows.
// ---------------------------------------------------------------------------
__global__ __launch_bounds__(1024) void small_levels(
    const float* __restrict__ W1, const float* __restrict__ b1,
    const float* __restrict__ W2, const float* __restrict__ b2,
    float* __restrict__ embs)
{
    __shared__ float Xs[16 * 2 * EMB];   // 16 KB
    __shared__ float Hs[16 * HID];       // 16 KB
    const int tid = threadIdx.x;

    for (int l = 4; l >= 0; --l) {
        const int p0 = (1 << l) - 1, n = 1 << l;
        for (int idx = tid; idx < n * 2 * EMB; idx += 1024)
            Xs[idx] = embs[(size_t)(2 * p0 + 1) * EMB + idx];
        __syncthreads();
        {   // GEMM1: n x 256 outputs; threads = 256 cols x 4 row groups
            const int j = tid & 255;
            const int rg = tid >> 8;                 // 0..3
            const int rpg = (n + 3) >> 2;
            const int r0 = rg * rpg;
            float acc[4];
#pragma unroll
            for (int i = 0; i < 4; ++i) acc[i] = b1[j];
#pragma unroll 4
            for (int k = 0; k < 2 * EMB; ++k) {
                float w = W1[k * HID + j];
#pragma unroll
                for (int i = 0; i < 4; ++i) acc[i] += Xs[(r0 + i) * 2 * EMB + k] * w;
            }
#pragma unroll
            for (int i = 0; i < 4; ++i) {
                int r = r0 + i;
                if (i < rpg && r < n) Hs[r * HID + j] = lrelu(acc[i]);
            }
        }
        __syncthreads();
        {   // GEMM2: n x 128 outputs; threads = 128 cols x 8 row groups
            const int j = tid & 127;
            const int rg = tid >> 7;                 // 0..7
            const int rpg = (n + 7) >> 3;
            const int r0 = rg * rpg;
            float acc[2];
            acc[0] = b2[j]; acc[1] = b2[j];
#pragma unroll 4
            for (int k = 0; k < HID; ++k) {
                float w = W2[k * EMB + j];
#pragma unroll
                for (int i = 0; i < 2; ++i) acc[i] += Hs[(r0 + i) * HID + k] * w;
            }
#pragma unroll
            for (int i = 0; i < 2; ++i) {
                int r = r0 + i;
                if (i < rpg && r < n) embs[(size_t)(p0 + r) * EMB + j] = lrelu(acc[i]);
            }
        }
        __syncthreads();
    }
}

// ---------------------------------------------------------------------------
extern "C" void kernel_launch(void* const* d_in, const int* in_sizes, int n_in,
                              void* d_out, int out_size, void* d_ws, size_t ws_size,
                              hipStream_t stream)
{
    const float* lv = (const float*)d_in[0];
    const float* We = (const float*)d_in[1];
    const float* be = (const float*)d_in[2];
    const float* W1 = (const float*)d_in[3];
    const float* b1 = (const float*)d_in[4];
    const float* W2 = (const float*)d_in[5];
    const float* b2 = (const float*)d_in[6];
    float* embs = (float*)d_out;

    leaf_embed<<<N_LEAVES / 16, 256, 0, stream>>>(lv, We, be, embs);
    for (int l = DEPTH - 1; l >= 5; --l) {
        const int p0 = (1 << l) - 1, n = 1 << l;
        level_mlp<<<n / 32, 256, 0, stream>>>(W1, b1, W2, b2, embs, p0);
    }
    small_levels<<<1, 1024, 0, stream>>>(W1, b1, W2, b2, embs);
}

// Round 2
// 1008.235 us; speedup vs baseline: 1.5771x; 1.5771x over previous
//
#include <hip/hip_runtime.h>

#define DEPTH 18
#define EMB 128
#define HID 256
#define VAL 32
#define N_LEAVES (1 << DEPTH)
#define LEAF_START (N_LEAVES - 1)

typedef _Float16 half8 __attribute__((ext_vector_type(8)));
typedef _Float16 half4 __attribute__((ext_vector_type(4)));
typedef float f32x4 __attribute__((ext_vector_type(4)));

__device__ __forceinline__ float lrelu(float x) { return x > 0.f ? x : 0.01f * x; }

// ---------------------------------------------------------------------------
// Prep: swizzle W1 (256x256) and W2 (256x128) into fp16 MFMA A-fragment order
// for the TRANSPOSED GEMMs (A = W^T, m = output col, k = contraction dim).
// Frag lane layout (16x16x32): lane holds A[m = lane&15][k = (lane>>4)*8 + jj].
// W1f frag id f = kb*16 + jt (kb: k-block of 32, jt: hid tile of 16)
//   value[jj] = W1[kb*32 + q*8 + jj][jt*16 + nn]   (q=lane>>4, nn=lane&15)
// W2f frag id f = kb*8 + ct (ct: out-col tile of 16)
//   value[jj] = W2[kb*32 + q*8 + jj][ct*16 + nn]
// ---------------------------------------------------------------------------
__global__ __launch_bounds__(256) void prep_weights(
    const float* __restrict__ W1, const float* __restrict__ W2,
    _Float16* __restrict__ W1f, _Float16* __restrict__ W2f)
{
    const int gid = blockIdx.x * 256 + threadIdx.x;   // 12288 total (8192 + 4096)
    const int lane = gid & 63;
    const int nn = lane & 15, q = lane >> 4;
    if (gid < 8192) {
        const int f = gid >> 6, kb = f >> 4, jt = f & 15;
        half8 v;
#pragma unroll
        for (int jj = 0; jj < 8; ++jj)
            v[jj] = (_Float16)W1[(kb * 32 + q * 8 + jj) * HID + jt * 16 + nn];
        *((half8*)W1f + gid) = v;
    } else {
        const int g = gid - 8192;
        const int f = g >> 6, kb = f >> 3, ct = f & 7;
        half8 v;
#pragma unroll
        for (int jj = 0; jj < 8; ++jj)
            v[jj] = (_Float16)W2[(kb * 32 + q * 8 + jj) * EMB + ct * 16 + nn];
        *((half8*)W2f + g) = v;
    }
}

// ---------------------------------------------------------------------------
// Leaf embedding: lrelu(leaf_values @ We + be) -> embs[LEAF_START..] (fp32)
// ---------------------------------------------------------------------------
__global__ __launch_bounds__(256) void leaf_embed(
    const float* __restrict__ lv, const float* __restrict__ We,
    const float* __restrict__ be, float* __restrict__ embs)
{
    __shared__ float lvs[16][VAL];
    const int j = threadIdx.x & 127;
    const int h = threadIdx.x >> 7;

    float w[VAL];
#pragma unroll
    for (int k = 0; k < VAL; ++k) w[k] = We[k * EMB + j];
    const float bj = be[j];

    const int leaf0 = blockIdx.x * 16;
    {
        const float* src = lv + (size_t)leaf0 * VAL;
        ((float*)lvs)[threadIdx.x]       = src[threadIdx.x];
        ((float*)lvs)[threadIdx.x + 256] = src[threadIdx.x + 256];
    }
    __syncthreads();

#pragma unroll
    for (int it = 0; it < 8; ++it) {
        const int ll = it * 2 + h;
        float acc = bj;
#pragma unroll
        for (int k4 = 0; k4 < VAL / 4; ++k4) {
            float4 x4 = *(const float4*)&lvs[ll][k4 * 4];
            acc += x4.x * w[k4*4] + x4.y * w[k4*4+1] + x4.z * w[k4*4+2] + x4.w * w[k4*4+3];
        }
        embs[(size_t)(LEAF_START + leaf0 + ll) * EMB + j] = lrelu(acc);
    }
}

// ---------------------------------------------------------------------------
// One tree level via fp16 MFMA, transposed dataflow. n >= 64, n % 64 == 0.
//   GEMM1': H^T = W1^T @ X^T   (D1[hid][row])
//   GEMM2': O^T = W2^T @ H^T   (D2[col][row])
// Block = 4 waves, each wave owns 16 rows (parents). X read fp32 directly from
// embs (children are the contiguous node range starting at 2*p0+1), converted
// to f16 in-register. H round-trips through a per-wave 16x264 f16 LDS tile
// (b64 writes / b128 reads, conflict-free with the +8 pad). Output written
// fp32 straight to embs.
// ---------------------------------------------------------------------------
__global__ __launch_bounds__(256) void level_mfma(
    const _Float16* __restrict__ W1f, const _Float16* __restrict__ W2f,
    const float* __restrict__ b1, const float* __restrict__ b2,
    float* __restrict__ embs, int p0)
{
    __shared__ _Float16 Hs[4][16][264];   // 33792 B
    const int tid  = threadIdx.x;
    const int w    = tid >> 6;
    const int lane = tid & 63;
    const int n    = lane & 15;   // row within wave strip / operand 16-index
    const int q    = lane >> 4;   // quad
    const int i0   = blockIdx.x * 64 + w * 16;

    // X row pointer for this lane (fp32, k-contiguous)
    const float* Xrow = embs + (size_t)(2 * p0 + 1) * EMB + (size_t)(i0 + n) * 256 + q * 8;

    // ---- GEMM1': accumulate H^T, bias-initialized ----
    f32x4 d1[16];
#pragma unroll
    for (int jt = 0; jt < 16; ++jt)
        d1[jt] = *(const f32x4*)(b1 + jt * 16 + q * 4);

#pragma unroll
    for (int kb = 0; kb < 8; ++kb) {
        f32x4 u = *(const f32x4*)(Xrow + kb * 32);
        f32x4 v = *(const f32x4*)(Xrow + kb * 32 + 4);
        half8 bfrag;
        bfrag[0] = (_Float16)u[0]; bfrag[1] = (_Float16)u[1];
        bfrag[2] = (_Float16)u[2]; bfrag[3] = (_Float16)u[3];
        bfrag[4] = (_Float16)v[0]; bfrag[5] = (_Float16)v[1];
        bfrag[6] = (_Float16)v[2]; bfrag[7] = (_Float16)v[3];
        const half8* wf = (const half8*)W1f + (size_t)kb * 16 * 64 + lane;
#pragma unroll
        for (int jt = 0; jt < 16; ++jt) {
            half8 a = wf[jt * 64];
            d1[jt] = __builtin_amdgcn_mfma_f32_16x16x32_f16(a, bfrag, d1[jt], 0, 0, 0);
        }
    }

    // ---- epilogue 1: lrelu, f16, store H^T tile to LDS (row-major H[n][hid]) ----
    _Float16* hrow = &Hs[w][n][0];
#pragma unroll
    for (int jt = 0; jt < 16; ++jt) {
        half4 h;
#pragma unroll
        for (int r = 0; r < 4; ++r) { float x = d1[jt][r]; h[r] = (_Float16)(x > 0.f ? x : 0.01f * x); }
        *(half4*)(hrow + jt * 16 + q * 4) = h;   // intra-wave only; no barrier needed
    }

    // ---- GEMM2': O^T = W2^T @ H^T ----
    f32x4 d2[8];
#pragma unroll
    for (int ct = 0; ct < 8; ++ct)
        d2[ct] = *(const f32x4*)(b2 + ct * 16 + q * 4);

#pragma unroll
    for (int kb = 0; kb < 8; ++kb) {
        half8 bfrag = *(const half8*)(hrow + kb * 32 + q * 8);
        const half8* wf = (const half8*)W2f + (size_t)kb * 8 * 64 + lane;
#pragma unroll
        for (int ct = 0; ct < 8; ++ct) {
            half8 a = wf[ct * 64];
            d2[ct] = __builtin_amdgcn_mfma_f32_16x16x32_f16(a, bfrag, d2[ct], 0, 0, 0);
        }
    }

    // ---- epilogue 2: lrelu, store fp32 rows to embs ----
    float* orow = embs + (size_t)(p0 + i0 + n) * EMB + q * 4;
#pragma unroll
    for (int ct = 0; ct < 8; ++ct) {
        f32x4 o;
#pragma unroll
        for (int r = 0; r < 4; ++r) { float x = d2[ct][r]; o[r] = x > 0.f ? x : 0.01f * x; }
        *(f32x4*)(orow + ct * 16) = o;
    }
}

// ---------------------------------------------------------------------------
// Levels 5..0 (n = 32..1, 63 nodes) in ONE block of 1024 threads, fp32.
// ---------------------------------------------------------------------------
__global__ __launch_bounds__(1024) void small_levels(
    const float* __restrict__ W1, const float* __restrict__ b1,
    const float* __restrict__ W2, const float* __restrict__ b2,
    float* __restrict__ embs)
{
    __shared__ float Xs[32 * 2 * EMB];   // 32 KB
    __shared__ float Hs[32 * HID];       // 32 KB
    const int tid = threadIdx.x;

    for (int l = 5; l >= 0; --l) {
        const int p0 = (1 << l) - 1, n = 1 << l;
        for (int idx = tid; idx < n * 2 * EMB; idx += 1024)
            Xs[idx] = embs[(size_t)(2 * p0 + 1) * EMB + idx];
        __syncthreads();
        {   // GEMM1: n x 256; 256 cols x 4 row groups, up to 8 rows/thread
            const int j = tid & 255;
            const int rg = tid >> 8;
            const int rpg = (n + 3) >> 2;          // <= 8
            const int r0 = rg * rpg;
            float acc[8];
#pragma unroll
            for (int i = 0; i < 8; ++i) acc[i] = b1[j];
#pragma unroll 4
            for (int k = 0; k < 2 * EMB; ++k) {
                float wv = W1[k * HID + j];
#pragma unroll
                for (int i = 0; i < 8; ++i) acc[i] += Xs[((r0 + i) & 31) * 2 * EMB + k] * wv;
            }
#pragma unroll
            for (int i = 0; i < 8; ++i) {
                int r = r0 + i;
                if (i < rpg && r < n) Hs[r * HID + j] = lrelu(acc[i]);
            }
        }
        __syncthreads();
        {   // GEMM2: n x 128; 128 cols x 8 row groups, up to 4 rows/thread
            const int j = tid & 127;
            const int rg = tid >> 7;
            const int rpg = (n + 7) >> 3;          // <= 4
            const int r0 = rg * rpg;
            float acc[4];
#pragma unroll
            for (int i = 0; i < 4; ++i) acc[i] = b2[j];
#pragma unroll 4
            for (int k = 0; k < HID; ++k) {
                float wv = W2[k * EMB + j];
#pragma unroll
                for (int i = 0; i < 4; ++i) acc[i] += Hs[((r0 + i) & 31) * HID + k] * wv;
            }
#pragma unroll
            for (int i = 0; i < 4; ++i) {
                int r = r0 + i;
                if (i < rpg && r < n) embs[(size_t)(p0 + r) * EMB + j] = lrelu(acc[i]);
            }
        }
        __syncthreads();
    }
}

// ---------------------------------------------------------------------------
extern "C" void kernel_launch(void* const* d_in, const int* in_sizes, int n_in,
                              void* d_out, int out_size, void* d_ws, size_t ws_size,
                              hipStream_t stream)
{
    const float* lv = (const float*)d_in[0];
    const float* We = (const float*)d_in[1];
    const float* be = (const float*)d_in[2];
    const float* W1 = (const float*)d_in[3];
    const float* b1 = (const float*)d_in[4];
    const float* W2 = (const float*)d_in[5];
    const float* b2 = (const float*)d_in[6];
    float* embs = (float*)d_out;

    _Float16* W1f = (_Float16*)d_ws;            // 65536 f16 = 128 KB
    _Float16* W2f = W1f + 65536;                // 32768 f16 = 64 KB

    prep_weights<<<48, 256, 0, stream>>>(W1, W2, W1f, W2f);
    leaf_embed<<<N_LEAVES / 16, 256, 0, stream>>>(lv, We, be, embs);
    for (int l = DEPTH - 1; l >= 6; --l) {
        const int p0 = (1 << l) - 1, n = 1 << l;
        level_mfma<<<n / 64, 256, 0, stream>>>(W1f, W2f, b1, b2, embs, p0);
    }
    small_levels<<<1, 1024, 0, stream>>>(W1, b1, W2, b2, embs);
}